// Round 6
// baseline (671.861 us; speedup 1.0000x reference)
//
#include <hip/hip_runtime.h>

#define N_NODES 8192
#define M_EDGES 2048
#define KK      16
#define QKD     256
#define VD      256
#define P_PAIRS 120   // 16*15/2
#define CAP2    32    // max member edges per node (avg 4)
#define NPART   64    // mean-reduction partials
#define FSTRIDE (QKD + 4)
#define SCALE   0.17677669529663687f   // (256/8)^-0.5
#define FBLKS   1024  // fused grid: 4 blocks/CU x 256 CU, co-resident (proven R5)

// ---------------- K0: zero ecounts/edone/wflag (24 KB) ----------------
__global__ void zero_prep(int* __restrict__ p, int count) {
    int i = blockIdx.x * blockDim.x + threadIdx.x;
    if (i < count) p[i] = 0;
}

// ---------------- K1: fused scan -> weights -> mean partials ----------------
// No grid barrier (R5 showed centralized barrier = ~123us each). Dataflow sync:
//   edge m ready  <=> edone[m]==16   (release-inc after enodes store)
//   w[m] ready    <=> wflag[m]==1    (release-store after w store)
// Block b owns edges {2b, 2b+1}; blocks b<NPART also own partial b.
// Spins wait only on A1/A2 work of other blocks, which completes unconditionally
// => no circular waits. All FBLKS blocks co-resident => progress guaranteed.
__global__ __launch_bounds__(256, 4) void fused_swm(
        const float4* __restrict__ adj4, const float* __restrict__ x1,
        const float* __restrict__ v,
        int* __restrict__ ecounts, int* __restrict__ edone,
        int* __restrict__ wflag,
        int* __restrict__ ncounts, int* __restrict__ enodes,
        int* __restrict__ nedges,
        float* __restrict__ w, float* __restrict__ partials) {
    __shared__ float f[KK][FSTRIDE];     // ~16.6 KB
    __shared__ int   ids[KK];
    __shared__ float part[P_PAIRS][2];
    __shared__ float d2s[P_PAIRS];
    __shared__ float sigma2;
    __shared__ float esum[4];
    __shared__ float wloc[M_EDGES / NPART];

    const int t      = threadIdx.x;
    const int gwave  = (blockIdx.x * blockDim.x + t) >> 6;
    const int nwaves = (gridDim.x * blockDim.x) >> 6;
    const int lane   = t & 63;

    // ---- A1: wave-per-row ballot scan of adj (coalesced float4, 67 MB once)
    {
        const unsigned long long below = (1ull << lane) - 1ull;
        for (int n = gwave; n < N_NODES; n += nwaves) {
            const float4* row = adj4 + n * (M_EDGES / 4);
            int base = 0;
            #pragma unroll
            for (int c = 0; c < M_EDGES / 4 / 64; ++c) {   // 8 chunks
                float4 a = row[c * 64 + lane];
                unsigned long long b0 = __ballot(a.x > 0.f);
                unsigned long long b1 = __ballot(a.y > 0.f);
                unsigned long long b2 = __ballot(a.z > 0.f);
                unsigned long long b3 = __ballot(a.w > 0.f);
                if ((b0 | b1 | b2 | b3) != 0ull) {
                    int pre = __popcll(b0 & below) + __popcll(b1 & below)
                            + __popcll(b2 & below) + __popcll(b3 & below);
                    int mbase = (c * 64 + lane) * 4;
                    float vals[4] = {a.x, a.y, a.z, a.w};
                    int own = 0;
                    #pragma unroll
                    for (int j = 0; j < 4; ++j) {
                        if (vals[j] > 0.f) {
                            int m = mbase + j;
                            int pos = base + pre + own;          // ascending-m
                            if (pos < CAP2) nedges[n * CAP2 + pos] = m;
                            int slot = __hip_atomic_fetch_add(&ecounts[m], 1,
                                          __ATOMIC_RELAXED, __HIP_MEMORY_SCOPE_AGENT);
                            if (slot < KK) enodes[m * KK + slot] = n;
                            // release AFTER the enodes store -> completion implies visibility
                            __hip_atomic_fetch_add(&edone[m], 1,
                                          __ATOMIC_RELEASE, __HIP_MEMORY_SCOPE_AGENT);
                            ++own;
                        }
                    }
                }
                base += __popcll(b0) + __popcll(b1) + __popcll(b2) + __popcll(b3);
            }
            if (lane == 0) ncounts[n] = base;
        }
    }

    // ---- A2: weights for this block's 2 owned edges
    for (int e = 0; e < 2; ++e) {
        int m = blockIdx.x * 2 + e;
        if (m >= M_EDGES) break;
        __syncthreads();   // protect LDS reuse
        if (t == 0) {
            while (__hip_atomic_load(&edone[m], __ATOMIC_ACQUIRE,
                                     __HIP_MEMORY_SCOPE_AGENT) < KK)
                __builtin_amdgcn_s_sleep(1);
        }
        __syncthreads();
        if (t < KK) ids[t] = enodes[m * KK + t];
        __syncthreads();
        if (t == 0) {      // sort -> deterministic order despite atomic scatter
            for (int a = 1; a < KK; ++a) {
                int x = ids[a]; int b = a - 1;
                while (b >= 0 && ids[b] > x) { ids[b + 1] = ids[b]; --b; }
                ids[b + 1] = x;
            }
        }
        __syncthreads();
        for (int k = 0; k < KK; ++k) f[k][t] = x1[ids[k] * QKD + t];
        __syncthreads();

        if (t < 2 * P_PAIRS) {          // pair split across 2 threads (128 dims each)
            int p = t >> 1, hh = t & 1;
            int i = 0, pp = p;
            while (pp >= KK - 1 - i) { pp -= KK - 1 - i; ++i; }
            int j = i + 1 + pp;
            const float4* fi = (const float4*)&f[i][0];
            const float4* fj = (const float4*)&f[j][0];
            int base4 = hh << 5;
            float acc = 0.0f;
            #pragma unroll 4
            for (int dd = 0; dd < 32; ++dd) {    // no stagger: lane-pairs broadcast
                float4 a = fi[base4 + dd], b = fj[base4 + dd];
                float dx = a.x - b.x, dy = a.y - b.y, dz = a.z - b.z, dw = a.w - b.w;
                acc += dx * dx + dy * dy + dz * dz + dw * dw;
            }
            part[p][hh] = acc;
        }
        __syncthreads();
        if (t < P_PAIRS) d2s[t] = part[t][0] + part[t][1];
        __syncthreads();

        if (t < P_PAIRS) {   // lower-median rank select (rank 59 of 120)
            float mine = d2s[t];
            int rank = 0;
            for (int q = 0; q < P_PAIRS; ++q) {
                float o = d2s[q];
                rank += (o < mine || (o == mine && q < t)) ? 1 : 0;
            }
            if (rank == (P_PAIRS - 1) / 2) sigma2 = mine * mine;
        }
        __syncthreads();

        float ev = (t < P_PAIRS) ? expf(-d2s[t] / sigma2) : 0.0f;
        ev += __shfl_xor(ev, 32); ev += __shfl_xor(ev, 16); ev += __shfl_xor(ev, 8);
        ev += __shfl_xor(ev, 4);  ev += __shfl_xor(ev, 2);  ev += __shfl_xor(ev, 1);
        if ((t & 63) == 0) esum[t >> 6] = ev;
        __syncthreads();
        if (t == 0) {
            w[m] = (esum[0] + esum[1] + esum[2] + esum[3]) / (float)(KK * (KK - 1));
            __threadfence();
            __hip_atomic_store(&wflag[m], 1, __ATOMIC_RELEASE, __HIP_MEMORY_SCOPE_AGENT);
        }
    }

    // ---- A3: partial sums of w*v (blocks 0..NPART-1), deterministic order
    if (blockIdx.x < NPART) {
        const int b = blockIdx.x;
        const int EPB = M_EDGES / NPART;   // 32
        if (t < EPB) {
            int m = b * EPB + t;
            while (__hip_atomic_load(&wflag[m], __ATOMIC_ACQUIRE,
                                     __HIP_MEMORY_SCOPE_AGENT) == 0)
                __builtin_amdgcn_s_sleep(1);
            wloc[t] = w[m];
        }
        __syncthreads();
        float acc = 0.0f;
        #pragma unroll 8
        for (int e = 0; e < EPB; ++e)
            acc += wloc[e] * v[(b * EPB + e) * VD + t];
        partials[b * VD + t] = acc;
    }
}

// ---------------- K2: attention, wave-per-node, shuffle-only online softmax ---
// lane l owns dims {l, l+64, l+128, l+192}; 32-lane-group reduce gives per-head
// scores (head of dim d = d>>5); no LDS, no block barriers.
__global__ __launch_bounds__(256) void attn(
        const float* __restrict__ x1, const float* __restrict__ x2,
        const float* __restrict__ v,  const float* __restrict__ w,
        const int* __restrict__ ncounts, const int* __restrict__ nedges,
        const float* __restrict__ partials, float* __restrict__ out) {
    const int gwave  = (blockIdx.x * blockDim.x + threadIdx.x) >> 6;
    const int nwaves = (gridDim.x * blockDim.x) >> 6;
    const int lane   = threadIdx.x & 63;

    for (int n = gwave; n < N_NODES; n += nwaves) {
        int C = ncounts[n]; if (C > CAP2) C = CAP2;
        const int* ned = nedges + n * CAP2;
        const float* xq = x1 + n * QKD;
        float q0 = xq[lane]       * SCALE;
        float q1 = xq[lane + 64]  * SCALE;
        float q2 = xq[lane + 128] * SCALE;
        float q3 = xq[lane + 192] * SCALE;
        float mk0 = -INFINITY, mk1 = -INFINITY, mk2 = -INFINITY, mk3 = -INFINITY;
        float l0 = 0, l1 = 0, l2 = 0, l3 = 0;
        float a0 = 0, a1 = 0, a2 = 0, a3 = 0;
        for (int c = 0; c < C; ++c) {
            int m = ned[c];
            float wm = w[m];
            const float* xr = x2 + m * QKD;
            const float* vr = v  + m * VD;
            float p0 = q0 * xr[lane],       p1 = q1 * xr[lane + 64];
            float p2 = q2 * xr[lane + 128], p3 = q3 * xr[lane + 192];
            #pragma unroll
            for (int s = 1; s < 32; s <<= 1) {
                p0 += __shfl_xor(p0, s); p1 += __shfl_xor(p1, s);
                p2 += __shfl_xor(p2, s); p3 += __shfl_xor(p3, s);
            }
            float v0 = vr[lane], v1 = vr[lane + 64], v2 = vr[lane + 128], v3 = vr[lane + 192];
            float nm, fac, e;
            nm = fmaxf(mk0, p0); fac = expf(mk0 - nm); e = expf(p0 - nm);
            l0 = l0 * fac + e; a0 = a0 * fac + e * wm * v0; mk0 = nm;
            nm = fmaxf(mk1, p1); fac = expf(mk1 - nm); e = expf(p1 - nm);
            l1 = l1 * fac + e; a1 = a1 * fac + e * wm * v1; mk1 = nm;
            nm = fmaxf(mk2, p2); fac = expf(mk2 - nm); e = expf(p2 - nm);
            l2 = l2 * fac + e; a2 = a2 * fac + e * wm * v2; mk2 = nm;
            nm = fmaxf(mk3, p3); fac = expf(mk3 - nm); e = expf(p3 - nm);
            l3 = l3 * fac + e; a3 = a3 * fac + e * wm * v3; mk3 = nm;
        }
        float o0, o1, o2, o3;
        if (C > 0) {
            o0 = a0 / l0; o1 = a1 / l1; o2 = a2 / l2; o3 = a3 / l3;
        } else {
            // empty row: softmax over all-NEG is uniform -> mean of w*v
            float s0 = 0, s1 = 0, s2 = 0, s3 = 0;
            #pragma unroll 8
            for (int b = 0; b < NPART; ++b) {
                const float* pp = partials + b * VD;
                s0 += pp[lane];       s1 += pp[lane + 64];
                s2 += pp[lane + 128]; s3 += pp[lane + 192];
            }
            const float inv = 1.0f / (float)M_EDGES;
            o0 = s0 * inv; o1 = s1 * inv; o2 = s2 * inv; o3 = s3 * inv;
        }
        float* op = out + n * VD;
        op[lane] = o0; op[lane + 64] = o1; op[lane + 128] = o2; op[lane + 192] = o3;
    }
}

extern "C" void kernel_launch(void* const* d_in, const int* in_sizes, int n_in,
                              void* d_out, int out_size, void* d_ws, size_t ws_size,
                              hipStream_t stream) {
    const float* x1  = (const float*)d_in[0];   // (N, 256)
    const float* x2  = (const float*)d_in[1];   // (M, 256)
    const float* v   = (const float*)d_in[2];   // (M, 256)
    const float* adj = (const float*)d_in[3];   // (N, M)
    float* out = (float*)d_out;                 // (N, 256)

    // workspace layout (all 4-byte elems), ~1.3 MB total
    float* w        = (float*)d_ws;                  // M
    float* partials = w + M_EDGES;                   // NPART*VD
    int*   ncounts  = (int*)(partials + NPART * VD); // N
    int*   enodes   = ncounts + N_NODES;             // M*KK
    int*   nedges   = enodes + M_EDGES * KK;         // N*CAP2
    int*   ecounts  = nedges + N_NODES * CAP2;       // M   } zeroed
    int*   edone    = ecounts + M_EDGES;             // M   } together
    int*   wflag    = edone + M_EDGES;               // M   }

    const int nzero = 3 * M_EDGES;
    zero_prep<<<(nzero + 255) / 256, 256, 0, stream>>>(ecounts, nzero);
    fused_swm<<<FBLKS, 256, 0, stream>>>((const float4*)adj, x1, v,
                                         ecounts, edone, wflag,
                                         ncounts, enodes, nedges, w, partials);
    attn<<<N_NODES / 4, 256, 0, stream>>>(x1, x2, v, w, ncounts, nedges, partials, out);
}

// Round 8
// 67.666 us; speedup vs baseline: 9.9291x; 9.9291x over previous
//
#include <hip/hip_runtime.h>

#define N_NODES 8192
#define M_EDGES 2048
#define KK      16
#define QKD     256
#define VD      256
#define P_PAIRS 120   // 16*15/2
#define CAP2    32    // max member edges per node (avg 4)
#define NPART   64    // mean-reduction partials
#define FSTRIDE (QKD + 4)
#define SCALE   0.17677669529663687f   // (256/8)^-0.5

typedef float floatx4 __attribute__((ext_vector_type(4)));  // plain vector type:
// __builtin_nontemporal_load accepts this (it rejects HIP_vector_type<float,4>)

// ---------------- K0: zero ecounts (8 KB) — cheap custom kernel ----------------
__global__ void zero_prep(int* __restrict__ p, int count) {
    int i = blockIdx.x * blockDim.x + threadIdx.x;
    if (i < count) p[i] = 0;
}

// ---------------- K1: wave-per-row ballot scan of adj ----------------
// One wave64 per node row; nontemporal float4 loads (adj is stream-once, keep
// L2 for x1/x2/v). nedges built in ascending-m order (deterministic, no
// node-side atomics); edge side uses atomics + later sort.
__global__ __launch_bounds__(256) void scan_adj(const floatx4* __restrict__ adj4,
                                                int* __restrict__ ecounts,
                                                int* __restrict__ enodes,
                                                int* __restrict__ ncounts,
                                                int* __restrict__ nedges) {
    int wid  = (blockIdx.x * blockDim.x + threadIdx.x) >> 6;   // node id
    int lane = threadIdx.x & 63;
    if (wid >= N_NODES) return;
    const floatx4* row = adj4 + wid * (M_EDGES / 4);
    unsigned long long below = (1ull << lane) - 1ull;
    int base = 0;
    #pragma unroll
    for (int c = 0; c < M_EDGES / 4 / 64; ++c) {        // 8 chunks, loads independent
        floatx4 a = __builtin_nontemporal_load(&row[c * 64 + lane]);
        unsigned long long b0 = __ballot(a.x > 0.f);
        unsigned long long b1 = __ballot(a.y > 0.f);
        unsigned long long b2 = __ballot(a.z > 0.f);
        unsigned long long b3 = __ballot(a.w > 0.f);
        if ((b0 | b1 | b2 | b3) != 0ull) {
            int pre = __popcll(b0 & below) + __popcll(b1 & below)
                    + __popcll(b2 & below) + __popcll(b3 & below);
            int mbase = (c * 64 + lane) * 4;
            float vals[4] = {a.x, a.y, a.z, a.w};
            int own = 0;
            #pragma unroll
            for (int j = 0; j < 4; ++j) {
                if (vals[j] > 0.f) {
                    int m = mbase + j;
                    int pos = base + pre + own;          // ascending-m position
                    if (pos < CAP2) nedges[wid * CAP2 + pos] = m;
                    int slot = atomicAdd(&ecounts[m], 1);
                    if (slot < KK) enodes[m * KK + slot] = wid;
                    ++own;
                }
            }
        }
        base += __popcll(b0) + __popcll(b1) + __popcll(b2) + __popcll(b3);
    }
    if (lane == 0) ncounts[wid] = base;
}

// ---------------- K2: per-edge weight w[m] ----------------
__global__ __launch_bounds__(256) void edge_weights(const float* __restrict__ x1,
                                                    const int* __restrict__ enodes,
                                                    float* __restrict__ w) {
    __shared__ float f[KK][FSTRIDE];   // 16.6 KB, float4-aligned rows (260*4 = 1040 = 65*16)
    __shared__ int   ids[KK];
    __shared__ float part[P_PAIRS][2];
    __shared__ float d2s[P_PAIRS];
    __shared__ float sigma2;
    __shared__ float esum[4];
    int m = blockIdx.x;
    int t = threadIdx.x;

    if (t < KK) ids[t] = enodes[m * KK + t];
    __syncthreads();
    if (t == 0) {      // sort -> deterministic order despite atomic scatter
        for (int a = 1; a < KK; ++a) {
            int x = ids[a]; int b = a - 1;
            while (b >= 0 && ids[b] > x) { ids[b + 1] = ids[b]; --b; }
            ids[b + 1] = x;
        }
    }
    __syncthreads();
    // float4 gather: 4 passes, 4 rows each; thread t -> row kb*4+(t>>6), col t&63
    #pragma unroll
    for (int kb = 0; kb < 4; ++kb) {
        int k = kb * 4 + (t >> 6);
        int c = t & 63;
        float4 val = ((const float4*)(x1 + ids[k] * QKD))[c];
        ((float4*)&f[k][0])[c] = val;
    }
    __syncthreads();

    if (t < 2 * P_PAIRS) {          // pair split across 2 threads (128 dims each)
        int p = t >> 1, hh = t & 1;
        int i = 0, pp = p;
        while (pp >= KK - 1 - i) { pp -= KK - 1 - i; ++i; }
        int j = i + 1 + pp;
        const float4* fi = (const float4*)&f[i][0];
        const float4* fj = (const float4*)&f[j][0];
        int base4 = hh << 5;
        float acc = 0.0f;
        #pragma unroll 4
        for (int dd = 0; dd < 32; ++dd) {
            float4 a = fi[base4 + dd], b = fj[base4 + dd];
            float dx = a.x - b.x, dy = a.y - b.y, dz = a.z - b.z, dw = a.w - b.w;
            acc += dx * dx + dy * dy + dz * dz + dw * dw;
        }
        part[p][hh] = acc;
    }
    __syncthreads();
    if (t < P_PAIRS) d2s[t] = part[t][0] + part[t][1];
    __syncthreads();

    if (t < P_PAIRS) {   // lower-median rank select (rank 59 of 120)
        float mine = d2s[t];
        int rank = 0;
        for (int q = 0; q < P_PAIRS; ++q) {
            float o = d2s[q];
            rank += (o < mine || (o == mine && q < t)) ? 1 : 0;
        }
        if (rank == (P_PAIRS - 1) / 2) sigma2 = mine * mine;
    }
    __syncthreads();

    float e = (t < P_PAIRS) ? expf(-d2s[t] / sigma2) : 0.0f;
    e += __shfl_xor(e, 32); e += __shfl_xor(e, 16); e += __shfl_xor(e, 8);
    e += __shfl_xor(e, 4);  e += __shfl_xor(e, 2);  e += __shfl_xor(e, 1);
    if ((t & 63) == 0) esum[t >> 6] = e;
    __syncthreads();
    if (t == 0) w[m] = (esum[0] + esum[1] + esum[2] + esum[3]) / (float)(KK * (KK - 1));
}

// ---------------- K3: deterministic partial sums of w[m]*v[m] ----------------
__global__ void mean_vv_part(const float* __restrict__ v, const float* __restrict__ w,
                             float* __restrict__ partials) {
    int t = threadIdx.x, b = blockIdx.x;   // NPART blocks x 32 edges each
    float acc = 0.0f;
    #pragma unroll 8
    for (int mm = 0; mm < M_EDGES / NPART; ++mm) {
        int m = b * (M_EDGES / NPART) + mm;
        acc += w[m] * v[m * VD + t];
    }
    partials[b * VD + t] = acc;
}

// ---------------- K4: attention, wave-per-node, float4 per-lane dims ----------
// Lane l owns dims 4l..4l+3 (all inside head l>>3). Head score = 8-lane reduce
// (xor 1,2,4). Per member edge: 2 float4 loads + 3 shuffles + 1 online-softmax
// chain. Deterministic (ascending-m nedges).
__global__ __launch_bounds__(256) void attn(
        const float* __restrict__ x1, const float* __restrict__ x2,
        const float* __restrict__ v,  const float* __restrict__ w,
        const int* __restrict__ ncounts, const int* __restrict__ nedges,
        const float* __restrict__ partials, float* __restrict__ out) {
    const int wid  = (blockIdx.x * blockDim.x + threadIdx.x) >> 6;  // node
    const int lane = threadIdx.x & 63;
    if (wid >= N_NODES) return;

    int C = ncounts[wid]; if (C > CAP2) C = CAP2;
    const int* ned = nedges + wid * CAP2;

    float4 q = ((const float4*)(x1 + wid * QKD))[lane];
    q.x *= SCALE; q.y *= SCALE; q.z *= SCALE; q.w *= SCALE;

    float mk = -INFINITY, lsum = 0.0f;
    float4 acc = {0.f, 0.f, 0.f, 0.f};
    for (int c = 0; c < C; ++c) {
        int m = ned[c];
        float wm = w[m];
        float4 k4 = ((const float4*)(x2 + m * QKD))[lane];
        float4 v4 = ((const float4*)(v  + m * VD))[lane];
        float p = q.x * k4.x + q.y * k4.y + q.z * k4.z + q.w * k4.w;
        p += __shfl_xor(p, 1);   // 8-lane group = one head (dims 32h..32h+31)
        p += __shfl_xor(p, 2);
        p += __shfl_xor(p, 4);
        float nm  = fmaxf(mk, p);
        float fac = expf(mk - nm);
        float e   = expf(p - nm);
        float ew  = e * wm;
        lsum = lsum * fac + e;
        acc.x = acc.x * fac + ew * v4.x;
        acc.y = acc.y * fac + ew * v4.y;
        acc.z = acc.z * fac + ew * v4.z;
        acc.w = acc.w * fac + ew * v4.w;
        mk = nm;
    }
    float4 o;
    if (C > 0) {
        float inv = 1.0f / lsum;
        o.x = acc.x * inv; o.y = acc.y * inv; o.z = acc.z * inv; o.w = acc.w * inv;
    } else {
        // empty row: softmax over all-NEG is uniform -> mean of w*v
        float4 s = {0.f, 0.f, 0.f, 0.f};
        #pragma unroll 8
        for (int b = 0; b < NPART; ++b) {
            float4 pp = ((const float4*)(partials + b * VD))[lane];
            s.x += pp.x; s.y += pp.y; s.z += pp.z; s.w += pp.w;
        }
        const float inv = 1.0f / (float)M_EDGES;
        o.x = s.x * inv; o.y = s.y * inv; o.z = s.z * inv; o.w = s.w * inv;
    }
    ((float4*)(out + wid * VD))[lane] = o;
}

extern "C" void kernel_launch(void* const* d_in, const int* in_sizes, int n_in,
                              void* d_out, int out_size, void* d_ws, size_t ws_size,
                              hipStream_t stream) {
    const float* x1  = (const float*)d_in[0];   // (N, 256)
    const float* x2  = (const float*)d_in[1];   // (M, 256)
    const float* v   = (const float*)d_in[2];   // (M, 256)
    const float* adj = (const float*)d_in[3];   // (N, M)
    float* out = (float*)d_out;                 // (N, 256)

    // workspace layout (all 4-byte elems), ~1.3 MB total
    float* w        = (float*)d_ws;                  // M
    float* partials = w + M_EDGES;                   // NPART*VD
    int*   ncounts  = (int*)(partials + NPART * VD); // N
    int*   enodes   = ncounts + N_NODES;             // M*KK
    int*   nedges   = enodes + M_EDGES * KK;         // N*CAP2
    int*   ecounts  = nedges + N_NODES * CAP2;       // M (zeroed)

    zero_prep<<<(M_EDGES + 255) / 256, 256, 0, stream>>>(ecounts, M_EDGES);
    scan_adj<<<N_NODES / 4, 256, 0, stream>>>((const floatx4*)adj, ecounts,
                                              enodes, ncounts, nedges);
    edge_weights<<<M_EDGES, 256, 0, stream>>>(x1, enodes, w);
    mean_vv_part<<<NPART, 256, 0, stream>>>(v, w, partials);
    attn<<<N_NODES / 4, 256, 0, stream>>>(x1, x2, v, w, ncounts, nedges, partials, out);
}

// Round 9
// 63.167 us; speedup vs baseline: 10.6363x; 1.0712x over previous
//
#include <hip/hip_runtime.h>

#define N_NODES 8192
#define M_EDGES 2048
#define KK      16
#define QKD     256
#define VD      256
#define P_PAIRS 120   // 16*15/2
#define CAP2    32    // max member edges per node (avg 4)
#define NPART   64    // mean-reduction partials
#define FSTRIDE (QKD + 4)
#define SCALE   0.17677669529663687f   // (256/8)^-0.5

typedef float floatx4 __attribute__((ext_vector_type(4)));  // plain vector type
// (__builtin_nontemporal_load rejects HIP_vector_type<float,4>)

// ---------------- K1: wave-per-row ballot scan of adj ----------------
// One wave64 per node row; nontemporal float4 loads (adj is stream-once).
// nedges built in ascending-m order (deterministic, no node-side atomics).
// Edge side: ticket-mod atomics -- NO zeroing needed: each edge gets exactly
// KK=16 increments per call, so atomicAdd tickets are consecutive and
// (ticket & 15) is a permutation of 0..15 regardless of ecounts' prior value
// (poison/accumulation safe). enodes order is atomic-order-dependent but
// edge_weights sorts ids -> deterministic downstream.
__global__ __launch_bounds__(256) void scan_adj(const floatx4* __restrict__ adj4,
                                                unsigned int* __restrict__ ecounts,
                                                int* __restrict__ enodes,
                                                int* __restrict__ ncounts,
                                                int* __restrict__ nedges) {
    int wid  = (blockIdx.x * blockDim.x + threadIdx.x) >> 6;   // node id
    int lane = threadIdx.x & 63;
    if (wid >= N_NODES) return;
    const floatx4* row = adj4 + wid * (M_EDGES / 4);
    unsigned long long below = (1ull << lane) - 1ull;
    int base = 0;
    #pragma unroll
    for (int c = 0; c < M_EDGES / 4 / 64; ++c) {        // 8 chunks, loads independent
        floatx4 a = __builtin_nontemporal_load(&row[c * 64 + lane]);
        unsigned long long b0 = __ballot(a.x > 0.f);
        unsigned long long b1 = __ballot(a.y > 0.f);
        unsigned long long b2 = __ballot(a.z > 0.f);
        unsigned long long b3 = __ballot(a.w > 0.f);
        if ((b0 | b1 | b2 | b3) != 0ull) {
            int pre = __popcll(b0 & below) + __popcll(b1 & below)
                    + __popcll(b2 & below) + __popcll(b3 & below);
            int mbase = (c * 64 + lane) * 4;
            float vals[4] = {a.x, a.y, a.z, a.w};
            int own = 0;
            #pragma unroll
            for (int j = 0; j < 4; ++j) {
                if (vals[j] > 0.f) {
                    int m = mbase + j;
                    int pos = base + pre + own;          // ascending-m position
                    if (pos < CAP2) nedges[wid * CAP2 + pos] = m;
                    unsigned int slot = atomicAdd(&ecounts[m], 1u) & (KK - 1);
                    enodes[m * KK + slot] = wid;
                    ++own;
                }
            }
        }
        base += __popcll(b0) + __popcll(b1) + __popcll(b2) + __popcll(b3);
    }
    if (lane == 0) ncounts[wid] = base;
}

// ---------------- K2: per-edge weight w[m] ----------------
__global__ __launch_bounds__(256) void edge_weights(const float* __restrict__ x1,
                                                    const int* __restrict__ enodes,
                                                    float* __restrict__ w) {
    __shared__ float f[KK][FSTRIDE];   // 16.6 KB, float4-aligned rows
    __shared__ int   ids[KK];
    __shared__ float part[P_PAIRS][2];
    __shared__ float d2s[P_PAIRS];
    __shared__ float sigma2;
    __shared__ float esum[4];
    int m = blockIdx.x;
    int t = threadIdx.x;

    if (t < KK) ids[t] = enodes[m * KK + t];
    __syncthreads();
    if (t == 0) {      // sort -> deterministic order despite atomic scatter
        for (int a = 1; a < KK; ++a) {
            int x = ids[a]; int b = a - 1;
            while (b >= 0 && ids[b] > x) { ids[b + 1] = ids[b]; --b; }
            ids[b + 1] = x;
        }
    }
    __syncthreads();
    // float4 gather: 4 passes, 4 rows each; thread t -> row kb*4+(t>>6), col t&63
    #pragma unroll
    for (int kb = 0; kb < 4; ++kb) {
        int k = kb * 4 + (t >> 6);
        int c = t & 63;
        float4 val = ((const float4*)(x1 + ids[k] * QKD))[c];
        ((float4*)&f[k][0])[c] = val;
    }
    __syncthreads();

    if (t < 2 * P_PAIRS) {          // pair split across 2 threads (128 dims each)
        int p = t >> 1, hh = t & 1;
        int i = 0, pp = p;
        while (pp >= KK - 1 - i) { pp -= KK - 1 - i; ++i; }
        int j = i + 1 + pp;
        const float4* fi = (const float4*)&f[i][0];
        const float4* fj = (const float4*)&f[j][0];
        int base4 = hh << 5;
        float acc = 0.0f;
        #pragma unroll 4
        for (int dd = 0; dd < 32; ++dd) {
            float4 a = fi[base4 + dd], b = fj[base4 + dd];
            float dx = a.x - b.x, dy = a.y - b.y, dz = a.z - b.z, dw = a.w - b.w;
            acc += dx * dx + dy * dy + dz * dz + dw * dw;
        }
        part[p][hh] = acc;
    }
    __syncthreads();
    if (t < P_PAIRS) d2s[t] = part[t][0] + part[t][1];
    __syncthreads();

    if (t < P_PAIRS) {   // lower-median rank select (rank 59 of 120)
        float mine = d2s[t];
        int rank = 0;
        for (int q = 0; q < P_PAIRS; ++q) {
            float o = d2s[q];
            rank += (o < mine || (o == mine && q < t)) ? 1 : 0;
        }
        if (rank == (P_PAIRS - 1) / 2) sigma2 = mine * mine;
    }
    __syncthreads();

    float e = (t < P_PAIRS) ? expf(-d2s[t] / sigma2) : 0.0f;
    e += __shfl_xor(e, 32); e += __shfl_xor(e, 16); e += __shfl_xor(e, 8);
    e += __shfl_xor(e, 4);  e += __shfl_xor(e, 2);  e += __shfl_xor(e, 1);
    if ((t & 63) == 0) esum[t >> 6] = e;
    __syncthreads();
    if (t == 0) w[m] = (esum[0] + esum[1] + esum[2] + esum[3]) / (float)(KK * (KK - 1));
}

// ---------------- K3: deterministic partial sums of w[m]*v[m] ----------------
__global__ void mean_vv_part(const float* __restrict__ v, const float* __restrict__ w,
                             float* __restrict__ partials) {
    int t = threadIdx.x, b = blockIdx.x;   // NPART blocks x 32 edges each
    float acc = 0.0f;
    #pragma unroll 8
    for (int mm = 0; mm < M_EDGES / NPART; ++mm) {
        int m = b * (M_EDGES / NPART) + mm;
        acc += w[m] * v[m * VD + t];
    }
    partials[b * VD + t] = acc;
}

// ---------------- K4: attention, wave-per-node, float4 per-lane dims ----------
// Lane l owns dims 4l..4l+3 (all inside head l>>3). Head score = 8-lane reduce
// (xor 1,2,4). Per member edge: 2 float4 loads + 3 shuffles + 1 online-softmax
// chain. Deterministic (ascending-m nedges).
__global__ __launch_bounds__(256) void attn(
        const float* __restrict__ x1, const float* __restrict__ x2,
        const float* __restrict__ v,  const float* __restrict__ w,
        const int* __restrict__ ncounts, const int* __restrict__ nedges,
        const float* __restrict__ partials, float* __restrict__ out) {
    const int wid  = (blockIdx.x * blockDim.x + threadIdx.x) >> 6;  // node
    const int lane = threadIdx.x & 63;
    if (wid >= N_NODES) return;

    int C = ncounts[wid]; if (C > CAP2) C = CAP2;
    const int* ned = nedges + wid * CAP2;

    float4 q = ((const float4*)(x1 + wid * QKD))[lane];
    q.x *= SCALE; q.y *= SCALE; q.z *= SCALE; q.w *= SCALE;

    float mk = -INFINITY, lsum = 0.0f;
    float4 acc = {0.f, 0.f, 0.f, 0.f};
    for (int c = 0; c < C; ++c) {
        int m = ned[c];
        float wm = w[m];
        float4 k4 = ((const float4*)(x2 + m * QKD))[lane];
        float4 v4 = ((const float4*)(v  + m * VD))[lane];
        float p = q.x * k4.x + q.y * k4.y + q.z * k4.z + q.w * k4.w;
        p += __shfl_xor(p, 1);   // 8-lane group = one head (dims 32h..32h+31)
        p += __shfl_xor(p, 2);
        p += __shfl_xor(p, 4);
        float nm  = fmaxf(mk, p);
        float fac = expf(mk - nm);
        float e   = expf(p - nm);
        float ew  = e * wm;
        lsum = lsum * fac + e;
        acc.x = acc.x * fac + ew * v4.x;
        acc.y = acc.y * fac + ew * v4.y;
        acc.z = acc.z * fac + ew * v4.z;
        acc.w = acc.w * fac + ew * v4.w;
        mk = nm;
    }
    float4 o;
    if (C > 0) {
        float inv = 1.0f / lsum;
        o.x = acc.x * inv; o.y = acc.y * inv; o.z = acc.z * inv; o.w = acc.w * inv;
    } else {
        // empty row: softmax over all-NEG is uniform -> mean of w*v
        float4 s = {0.f, 0.f, 0.f, 0.f};
        #pragma unroll 8
        for (int b = 0; b < NPART; ++b) {
            float4 pp = ((const float4*)(partials + b * VD))[lane];
            s.x += pp.x; s.y += pp.y; s.z += pp.z; s.w += pp.w;
        }
        const float inv = 1.0f / (float)M_EDGES;
        o.x = s.x * inv; o.y = s.y * inv; o.z = s.z * inv; o.w = s.w * inv;
    }
    ((float4*)(out + wid * VD))[lane] = o;
}

extern "C" void kernel_launch(void* const* d_in, const int* in_sizes, int n_in,
                              void* d_out, int out_size, void* d_ws, size_t ws_size,
                              hipStream_t stream) {
    const float* x1  = (const float*)d_in[0];   // (N, 256)
    const float* x2  = (const float*)d_in[1];   // (M, 256)
    const float* v   = (const float*)d_in[2];   // (M, 256)
    const float* adj = (const float*)d_in[3];   // (N, M)
    float* out = (float*)d_out;                 // (N, 256)

    // workspace layout (all 4-byte elems), ~1.3 MB total; nothing needs zeroing
    float* w        = (float*)d_ws;                  // M
    float* partials = w + M_EDGES;                   // NPART*VD
    int*   ncounts  = (int*)(partials + NPART * VD); // N
    int*   enodes   = ncounts + N_NODES;             // M*KK
    int*   nedges   = enodes + M_EDGES * KK;         // N*CAP2
    unsigned int* ecounts = (unsigned int*)(nedges + N_NODES * CAP2); // M (ticket-mod, no init)

    scan_adj<<<N_NODES / 4, 256, 0, stream>>>((const floatx4*)adj, ecounts,
                                              enodes, ncounts, nedges);
    edge_weights<<<M_EDGES, 256, 0, stream>>>(x1, enodes, w);
    mean_vv_part<<<NPART, 256, 0, stream>>>(v, w, partials);
    attn<<<N_NODES / 4, 256, 0, stream>>>(x1, x2, v, w, ncounts, nedges, partials, out);
}